// Round 7
// baseline (706.272 us; speedup 1.0000x reference)
//
#include <hip/hip_runtime.h>

// GCN encoder: h = relu(A_norm @ (x@W1) + b1); mean = (A_norm@h)@W2+b2; logstd = (A_norm@h)@W3+b3
// R2: 3-stage parallel scan. R3/R4: spmm ping-pong software pipeline (161->108us).
// R5: packed u64 atomic histogram -> atomic-free fill. R6: split-bf16 MFMA gemm1 (129->~45us).
// R7: spmm beyond-L2 path saturated (~3.5 TB/s, FETCH 366MB vs 25.6MB features): channel-sliced
//     XCD-pinned spmm — 8 slices of 16 ch (3.2MB, L2-resident per XCD via blockIdx%8),
//     4 nodes per wave (16 lanes/node), gathers become L2 hits.

#define THREADS 256
#define SCAN_CHUNK 2048   // elements per block in the scan kernels (256 thr x 8)
#define D 4               // spmm pipeline group size (2 groups in flight)
#define NSLICE 8
#define TILE 16           // channels per slice (16 f32 = 64 B)
#define NPB 16            // nodes per block (4 waves x 4 nodes)

#define DEG_MASK ((1ULL << 40) - 1)
#define CNT_SHIFT 40

typedef __attribute__((ext_vector_type(8))) short short8;   // 8 bf16 (4 VGPRs)
typedef __attribute__((ext_vector_type(4))) float floatx4;  // MFMA acc

// ---------------- zero init (ws is poisoned 0xAA every launch) ----------------
__global__ __launch_bounds__(THREADS) void zero_kernel(float* __restrict__ p, int n) {
    int i = blockIdx.x * THREADS + threadIdx.x;
    if (i < n) p[i] = 0.0f;   // bit pattern 0 also valid for u64 packed counters
}

// ---------------- fused histogram: one u64 atomic per edge, returns rank ----------------
__global__ __launch_bounds__(THREADS) void deg_count_kernel(
    const int* __restrict__ ei, const float* __restrict__ ew,
    unsigned long long* __restrict__ deg_cnt, int* __restrict__ rank, int E) {
    int e = blockIdx.x * THREADS + threadIdx.x;
    if (e >= E) return;
    int d = ei[E + e];                 // dst row of edge_index
    float w = ew[e];
    unsigned long long q = (unsigned long long)(w * 4294967296.0f);  // w in [0,1) -> 33 bits
    unsigned long long old = atomicAdd(&deg_cnt[d], (1ULL << CNT_SHIFT) | q);
    rank[e] = (int)(old >> CNT_SHIFT); // # prior edges to this dst = slot within CSR row
}

// ---------------- parallel scan stage 1: block sums + dinv ----------------
__global__ __launch_bounds__(THREADS) void scan_part1(
    const unsigned long long* __restrict__ deg_cnt,
    float* __restrict__ dinvv, int* __restrict__ partials, int n) {
    int t = threadIdx.x;
    int base = blockIdx.x * SCAN_CHUNK + t * 8;
    int s = 0;
#pragma unroll
    for (int i = 0; i < 8; ++i) {
        int idx = base + i;
        if (idx < n) {
            unsigned long long v = deg_cnt[idx];
            s += (int)(v >> CNT_SHIFT);
            float dg = (float)(v & DEG_MASK) * 0x1p-32f;   // un-fixed-point the weight sum
            dinvv[idx] = rsqrtf(dg + 1.0f);                // +1 = self-loop weight
        }
    }
    __shared__ int sm[THREADS];
    sm[t] = s;
    __syncthreads();
    for (int off = THREADS / 2; off > 0; off >>= 1) {
        if (t < off) sm[t] += sm[t + off];
        __syncthreads();
    }
    if (t == 0) partials[blockIdx.x] = sm[0];
}

// ---------------- parallel scan stage 2: exclusive scan of block partials ----------------
__global__ __launch_bounds__(1024) void scan_part2(int* __restrict__ partials, int nb) {
    __shared__ int s[1024];
    int t = threadIdx.x;
    int v = (t < nb) ? partials[t] : 0;
    s[t] = v;
    __syncthreads();
    for (int off = 1; off < 1024; off <<= 1) {
        int x = (t >= off) ? s[t - off] : 0;
        __syncthreads();
        s[t] += x;
        __syncthreads();
    }
    if (t < nb) partials[t] = s[t] - v;   // exclusive prefix
}

// ---------------- parallel scan stage 3: per-block local scan -> offs ----------------
__global__ __launch_bounds__(THREADS) void scan_part3(
    const unsigned long long* __restrict__ deg_cnt, const int* __restrict__ partials,
    int* __restrict__ offs, int n) {
    int t = threadIdx.x;
    int base = blockIdx.x * SCAN_CHUNK + t * 8;
    int loc[8];
    int s = 0;
#pragma unroll
    for (int i = 0; i < 8; ++i) {
        int idx = base + i;
        int c = (idx < n) ? (int)(deg_cnt[idx] >> CNT_SHIFT) : 0;
        loc[i] = c;
        s += c;
    }
    __shared__ int sm[THREADS];
    sm[t] = s;
    __syncthreads();
    for (int off = 1; off < THREADS; off <<= 1) {
        int x = (t >= off) ? sm[t - off] : 0;
        __syncthreads();
        sm[t] += x;
        __syncthreads();
    }
    int run = partials[blockIdx.x] + sm[t] - s;   // exclusive prefix of this thread's range
#pragma unroll
    for (int i = 0; i < 8; ++i) {
        int idx = base + i;
        if (idx < n) {
            offs[idx] = run;
            run += loc[i];
            if (idx == n - 1) offs[n] = run;
        }
    }
}

// ---------------- fill CSR: atomic-free (pos = offs[dst] + rank) ----------------
__global__ __launch_bounds__(THREADS) void fill_kernel(
    const int* __restrict__ ei, const float* __restrict__ ew,
    const float* __restrict__ dinvv, const int* __restrict__ offs,
    const int* __restrict__ rank, int2* __restrict__ csr, int E) {
    int e = blockIdx.x * THREADS + threadIdx.x;
    if (e >= E) return;
    int s = ei[e], d = ei[E + e];
    int pos = offs[d] + rank[e];
    csr[pos] = make_int2(s, __float_as_int(dinvv[s] * ew[e] * dinvv[d]));
}

// ---------------- W1 split+transpose: Wt_hi/lo[n=128][k=512] bf16 ----------------
__global__ __launch_bounds__(THREADS) void wsplit_kernel(
    const float* __restrict__ W, unsigned short* __restrict__ hi,
    unsigned short* __restrict__ lo) {
    int id = blockIdx.x * THREADS + threadIdx.x;   // 65536 = 512*128
    if (id >= 512 * 128) return;
    int k = id >> 7, n = id & 127;
    float v = W[id];                               // W[k][n]
    unsigned int b = __float_as_uint(v);
    unsigned short h = (unsigned short)(b >> 16);  // truncated hi bf16
    float fh = __uint_as_float(b & 0xFFFF0000u);
    unsigned short l = (unsigned short)(__float_as_uint(v - fh) >> 16);  // residual bf16
    hi[n * 512 + k] = h;
    lo[n * 512 + k] = l;
}

// ---------------- GEMM1 (MFMA): h0[M,128] = x[M,512] @ W1[512,128] ----------------
// Split-bf16: x = xh + xl, w = wh + wl; acc += xh*wh + xh*wl + xl*wh (err ~2^-17).
// BM=64, BN=128, BK=64; 4 waves in 2x2; per wave 32x64 = 2x4 frags of 16x16x32.
__global__ __launch_bounds__(THREADS) void gemm1_mfma_kernel(
    const float* __restrict__ A, const unsigned short* __restrict__ Wth,
    const unsigned short* __restrict__ Wtl, float* __restrict__ C, int M) {
    __shared__ unsigned short As[2][64][72];    // [hi/lo][m][k]
    __shared__ unsigned short Bs[2][128][72];   // [hi/lo][n][k]
    int t = threadIdx.x;
    int brow0 = blockIdx.x * 64;
    int arow = t >> 2, akq = (t & 3) * 16;      // A: 64 rows x 4 chunks of 16 f32
    int bn = t >> 1, bkoff = (t & 1) * 32;      // B: 128 rows x 2 chunks of 32 bf16
    int wid = t >> 6, lane = t & 63;
    int wr = wid >> 1, wc = wid & 1;            // 2x2 wave grid
    int lm = lane & 15, lk = (lane >> 4) * 8;
    floatx4 acc[2][4];
#pragma unroll
    for (int i = 0; i < 2; i++)
#pragma unroll
        for (int j = 0; j < 4; j++) acc[i][j] = (floatx4)0.0f;

    int gr = brow0 + arow;
    for (int k0 = 0; k0 < 512; k0 += 64) {
        __syncthreads();
        {
            const float* ap = &A[(size_t)gr * 512 + k0 + akq];
#pragma unroll
            for (int i = 0; i < 4; ++i) {
                float4 v = (gr < M) ? *(const float4*)&ap[i * 4]
                                    : make_float4(0.f, 0.f, 0.f, 0.f);
                float e[4] = {v.x, v.y, v.z, v.w};
                ushort4 h4, l4;
                unsigned short* hp = (unsigned short*)&h4;
                unsigned short* lp = (unsigned short*)&l4;
#pragma unroll
                for (int c = 0; c < 4; ++c) {
                    unsigned int b = __float_as_uint(e[c]);
                    hp[c] = (unsigned short)(b >> 16);
                    float fh = __uint_as_float(b & 0xFFFF0000u);
                    lp[c] = (unsigned short)(__float_as_uint(e[c] - fh) >> 16);
                }
                *(ushort4*)&As[0][arow][akq + i * 4] = h4;
                *(ushort4*)&As[1][arow][akq + i * 4] = l4;
            }
        }
        {
            const unsigned short* bh = &Wth[(size_t)bn * 512 + k0 + bkoff];
            const unsigned short* bl = &Wtl[(size_t)bn * 512 + k0 + bkoff];
#pragma unroll
            for (int s = 0; s < 4; ++s) {
                *(float4*)&Bs[0][bn][bkoff + s * 8] = *(const float4*)&bh[s * 8];
                *(float4*)&Bs[1][bn][bkoff + s * 8] = *(const float4*)&bl[s * 8];
            }
        }
        __syncthreads();
#pragma unroll
        for (int kc = 0; kc < 2; ++kc) {
            int kb = kc * 32 + lk;
            short8 ah[2], al[2], bh[4], bl[4];
#pragma unroll
            for (int mf = 0; mf < 2; ++mf) {
                ah[mf] = *(const short8*)&As[0][wr * 32 + mf * 16 + lm][kb];
                al[mf] = *(const short8*)&As[1][wr * 32 + mf * 16 + lm][kb];
            }
#pragma unroll
            for (int nf = 0; nf < 4; ++nf) {
                bh[nf] = *(const short8*)&Bs[0][wc * 64 + nf * 16 + lm][kb];
                bl[nf] = *(const short8*)&Bs[1][wc * 64 + nf * 16 + lm][kb];
            }
#pragma unroll
            for (int mf = 0; mf < 2; ++mf)
#pragma unroll
                for (int nf = 0; nf < 4; ++nf) {
                    acc[mf][nf] = __builtin_amdgcn_mfma_f32_16x16x32_bf16(
                        ah[mf], bh[nf], acc[mf][nf], 0, 0, 0);
                    acc[mf][nf] = __builtin_amdgcn_mfma_f32_16x16x32_bf16(
                        ah[mf], bl[nf], acc[mf][nf], 0, 0, 0);
                    acc[mf][nf] = __builtin_amdgcn_mfma_f32_16x16x32_bf16(
                        al[mf], bh[nf], acc[mf][nf], 0, 0, 0);
                }
        }
    }
#pragma unroll
    for (int mf = 0; mf < 2; ++mf) {
        int rbase = brow0 + wr * 32 + mf * 16 + (lane >> 4) * 4;
#pragma unroll
        for (int nf = 0; nf < 4; ++nf) {
            int col = wc * 64 + nf * 16 + lm;
#pragma unroll
            for (int r = 0; r < 4; ++r) {
                int g = rbase + r;
                if (g < M) C[(size_t)g * 128 + col] = acc[mf][nf][r];
            }
        }
    }
}

// ---------------- SpMM (channel-sliced, XCD-pinned) ----------------
// slice = blockIdx%8 -> pins each 16-channel slice (3.2MB) to one XCD's L2.
// 4 nodes per wave (lane groups of 16); per-lane D=4 ping-pong pipeline;
// short rows handled by w=0 masking against wave-max degree.
__global__ __launch_bounds__(THREADS) void spmm_x_kernel(
    const float* __restrict__ feat, const float* __restrict__ dinvv,
    const int* __restrict__ offs, const int2* __restrict__ csr,
    const float* __restrict__ bias, float* __restrict__ out, int n, int do_relu) {
    int slice = blockIdx.x & (NSLICE - 1);
    int chunk = blockIdx.x / NSLICE;
    int t = threadIdx.x;
    int wave = t >> 6, lane = t & 63;
    int node = chunk * NPB + wave * 4 + (lane >> 4);
    bool valid = node < n;
    int nd = valid ? node : (n - 1);
    int ch = slice * TILE + (lane & 15);
    const float* __restrict__ fb = feat + ch;

    float di = dinvv[nd];
    float acc = fb[(size_t)nd * 128] * di * di;     // self-loop term
    int j0 = offs[nd];
    int m = valid ? (offs[nd + 1] - j0) : 0;
    const int2* __restrict__ cp = csr + ((m > 0) ? j0 : 0);
    // wave-max degree (groups differ at lane-xor 16/32)
    int mm = m;
    mm = max(mm, __shfl_xor(mm, 16));
    mm = max(mm, __shfl_xor(mm, 32));

    int2 eA[D], eB[D];
    float wA[D], wB[D], vA[D], vB[D];
    // clamp OOB slots to edge 0 of the row (valid address); weight masked to 0
#define LD_E(jj) cp[((jj) < m) ? (jj) : 0]
#define MASK_W(jj, e) (((jj) < m) ? __int_as_float((e).y) : 0.0f)

#pragma unroll
    for (int i = 0; i < D; ++i) eA[i] = LD_E(i);
#pragma unroll
    for (int i = 0; i < D; ++i) eB[i] = LD_E(D + i);
#pragma unroll
    for (int i = 0; i < D; ++i) {
        wA[i] = MASK_W(i, eA[i]);
        vA[i] = fb[(size_t)eA[i].x * 128];
    }

    int g = 0;
    for (; g + 4 * D <= mm; g += 2 * D) {
#pragma unroll
        for (int i = 0; i < D; ++i) eA[i] = LD_E(g + 2 * D + i);
#pragma unroll
        for (int i = 0; i < D; ++i) {
            wB[i] = MASK_W(g + D + i, eB[i]);
            vB[i] = fb[(size_t)eB[i].x * 128];
        }
#pragma unroll
        for (int i = 0; i < D; ++i) acc = fmaf(wA[i], vA[i], acc);
#pragma unroll
        for (int i = 0; i < D; ++i) eB[i] = LD_E(g + 3 * D + i);
#pragma unroll
        for (int i = 0; i < D; ++i) {
            wA[i] = MASK_W(g + 2 * D + i, eA[i]);
            vA[i] = fb[(size_t)eA[i].x * 128];
        }
#pragma unroll
        for (int i = 0; i < D; ++i) acc = fmaf(wB[i], vB[i], acc);
    }
    // epilogue: group g resident in vA/wA; csr for group g+D resident in eB
#pragma unroll
    for (int i = 0; i < D; ++i) if (g + i < mm) acc = fmaf(wA[i], vA[i], acc);
    g += D;
#pragma unroll
    for (int i = 0; i < D; ++i) if (g + i < mm) {
        float w = MASK_W(g + i, eB[i]);
        acc = fmaf(w, fb[(size_t)eB[i].x * 128], acc);
    }
    g += D;
    for (; g < mm; ++g) {
        int2 e = LD_E(g);
        float w = MASK_W(g, e);
        acc = fmaf(w, fb[(size_t)e.x * 128], acc);
    }
#undef LD_E
#undef MASK_W

    if (bias) acc += bias[ch];
    if (do_relu) acc = fmaxf(acc, 0.0f);
    if (valid) out[(size_t)node * 128 + ch] = acc;
}

// ---------------- GEMM23: [mean|logstd] = agg2[M,128] @ [W2|W3][128,128] + [b2|b3] ------
__global__ __launch_bounds__(THREADS) void gemm23_kernel(
    const float* __restrict__ A, const float* __restrict__ W2,
    const float* __restrict__ W3, const float* __restrict__ b2,
    const float* __restrict__ b3, float* __restrict__ outm,
    float* __restrict__ outl, int M) {
    __shared__ float As[16][68];
    __shared__ float Bs[16][128];
    int t = threadIdx.x;
    int ty = t >> 4, tx = t & 15;
    int brow0 = blockIdx.x * 64;
    int arow = t >> 2, aq = t & 3;
    int bkr = t >> 5, bcol = (t & 31) * 4;
    float acc[4][8];
#pragma unroll
    for (int i = 0; i < 4; i++)
#pragma unroll
        for (int j = 0; j < 8; j++) acc[i][j] = 0.0f;
    int gr = brow0 + arow;
    const float4 z4 = make_float4(0.f, 0.f, 0.f, 0.f);
    for (int k0 = 0; k0 < 128; k0 += 16) {
        float4 av = (gr < M) ? *(const float4*)&A[(size_t)gr * 128 + k0 + aq * 4] : z4;
        int k1 = k0 + bkr, k2 = k0 + bkr + 8;
        float4 b0 = (bcol < 64) ? *(const float4*)&W2[(size_t)k1 * 64 + bcol]
                                : *(const float4*)&W3[(size_t)k1 * 64 + bcol - 64];
        float4 b1 = (bcol < 64) ? *(const float4*)&W2[(size_t)k2 * 64 + bcol]
                                : *(const float4*)&W3[(size_t)k2 * 64 + bcol - 64];
        __syncthreads();
        As[aq * 4 + 0][arow] = av.x;
        As[aq * 4 + 1][arow] = av.y;
        As[aq * 4 + 2][arow] = av.z;
        As[aq * 4 + 3][arow] = av.w;
        *(float4*)&Bs[bkr][bcol] = b0;
        *(float4*)&Bs[bkr + 8][bcol] = b1;
        __syncthreads();
#pragma unroll
        for (int kk = 0; kk < 16; ++kk) {
            float4 a = *(const float4*)&As[kk][ty * 4];
            float4 p0 = *(const float4*)&Bs[kk][tx * 8];
            float4 p1 = *(const float4*)&Bs[kk][tx * 8 + 4];
            float av_[4] = {a.x, a.y, a.z, a.w};
            float bv_[8] = {p0.x, p0.y, p0.z, p0.w, p1.x, p1.y, p1.z, p1.w};
#pragma unroll
            for (int i = 0; i < 4; i++)
#pragma unroll
                for (int j = 0; j < 8; j++)
                    acc[i][j] = fmaf(av_[i], bv_[j], acc[i][j]);
        }
    }
    bool is_mean = (tx < 8);
    int c = is_mean ? tx * 8 : tx * 8 - 64;
    const float* bb = is_mean ? b2 : b3;
    float* op = is_mean ? outm : outl;
    float4 bias0 = *(const float4*)&bb[c];
    float4 bias1 = *(const float4*)&bb[c + 4];
#pragma unroll
    for (int i = 0; i < 4; i++) {
        int r = brow0 + ty * 4 + i;
        if (r < M) {
            *(float4*)&op[(size_t)r * 64 + c] =
                make_float4(acc[i][0] + bias0.x, acc[i][1] + bias0.y,
                            acc[i][2] + bias0.z, acc[i][3] + bias0.w);
            *(float4*)&op[(size_t)r * 64 + c + 4] =
                make_float4(acc[i][4] + bias1.x, acc[i][5] + bias1.y,
                            acc[i][6] + bias1.z, acc[i][7] + bias1.w);
        }
    }
}

extern "C" void kernel_launch(void* const* d_in, const int* in_sizes, int n_in,
                              void* d_out, int out_size, void* d_ws, size_t ws_size,
                              hipStream_t stream) {
    const float* x  = (const float*)d_in[0];
    const int*   ei = (const int*)d_in[1];
    const float* ew = (const float*)d_in[2];
    const float* W1 = (const float*)d_in[3];
    const float* b1 = (const float*)d_in[4];
    const float* W2 = (const float*)d_in[5];
    const float* b2 = (const float*)d_in[6];
    const float* W3 = (const float*)d_in[7];
    const float* b3 = (const float*)d_in[8];

    const int n = in_sizes[0] / 512;   // 50000
    const int E = in_sizes[2];         // 1600000
    const int nb_scan = (n + SCAN_CHUNK - 1) / SCAN_CHUNK;   // 25

    char* p = (char*)d_ws;
    auto alloc = [&](size_t bytes) {
        char* q = p;
        p += (bytes + 511) & ~(size_t)511;
        return q;
    };
    unsigned long long* deg_cnt = (unsigned long long*)alloc((size_t)n * 8);
    float* dinvv  = (float*)alloc((size_t)n * 4);
    int*   offs   = (int*)alloc((size_t)(n + 1) * 4);
    int*   rank   = (int*)alloc((size_t)E * 4);
    int*   partials = (int*)alloc((size_t)nb_scan * 4);
    int2*  csr    = (int2*)alloc((size_t)E * 8);
    unsigned short* Wth = (unsigned short*)alloc((size_t)512 * 128 * 2);
    unsigned short* Wtl = (unsigned short*)alloc((size_t)512 * 128 * 2);
    float* h0     = (float*)alloc((size_t)n * 128 * 4);  // xW1, later reused as agg2
    float* hb     = (float*)alloc((size_t)n * 128 * 4);  // relu'd hidden
    float* agg2   = h0;

    float* outm = (float*)d_out;
    float* outl = outm + (size_t)n * 64;

    const int spmm_grid = ((n + NPB - 1) / NPB) * NSLICE;   // 3125 * 8 = 25000

    zero_kernel<<<(2 * n + THREADS - 1) / THREADS, THREADS, 0, stream>>>((float*)deg_cnt, 2 * n);
    deg_count_kernel<<<(E + THREADS - 1) / THREADS, THREADS, 0, stream>>>(ei, ew, deg_cnt, rank, E);
    scan_part1<<<nb_scan, THREADS, 0, stream>>>(deg_cnt, dinvv, partials, n);
    scan_part2<<<1, 1024, 0, stream>>>(partials, nb_scan);
    scan_part3<<<nb_scan, THREADS, 0, stream>>>(deg_cnt, partials, offs, n);
    fill_kernel<<<(E + THREADS - 1) / THREADS, THREADS, 0, stream>>>(ei, ew, dinvv, offs,
                                                                     rank, csr, E);
    wsplit_kernel<<<(512 * 128 + THREADS - 1) / THREADS, THREADS, 0, stream>>>(W1, Wth, Wtl);
    gemm1_mfma_kernel<<<(n + 63) / 64, THREADS, 0, stream>>>(x, Wth, Wtl, h0, n);
    spmm_x_kernel<<<spmm_grid, THREADS, 0, stream>>>(h0, dinvv, offs, csr, b1, hb, n, 1);
    spmm_x_kernel<<<spmm_grid, THREADS, 0, stream>>>(hb, dinvv, offs, csr, nullptr, agg2, n, 0);
    gemm23_kernel<<<(n + 63) / 64, THREADS, 0, stream>>>(agg2, W2, W3, b2, b3, outm, outl, n);
}

// Round 9
// 631.049 us; speedup vs baseline: 1.1192x; 1.1192x over previous
//
#include <hip/hip_runtime.h>

// GCN encoder: h = relu(A_norm @ (x@W1) + b1); mean = (A_norm@h)@W2+b2; logstd = (A_norm@h)@W3+b3
// R2: 3-stage parallel scan. R3/R4: spmm ping-pong pipeline (161->108us).
// R5: packed u64 atomic histogram -> atomic-free fill. R6: split-bf16 MFMA gemm1 (129->~45us).
// R7: channel-sliced spmm REGRESSED (177us): TILE=16 in row-major layout -> 128B-line
//     footprint 6.4MB > 4MiB L2 (never resident) + float1 gathers (VALU 41%).
// R8: SLAB layout hs[8][n][16] (3.2MB contiguous per slice -> truly L2-residency-sized),
//     slice pinned to XCD via blockIdx%8; float4 gathers (4 lanes/node, 16 nodes/wave).
// R9: R8 resubmit — FMA4 macro param 'w' collided with member '.w' (compile error); now
//     an inline function.

#define THREADS 256
#define SCAN_CHUNK 2048   // elements per block in the scan kernels (256 thr x 8)
#define D 4               // spmm pipeline group size (2 groups in flight)
#define NSLICE 8
#define NPB 64            // nodes per block (4 waves x 16 nodes)

#define DEG_MASK ((1ULL << 40) - 1)
#define CNT_SHIFT 40

typedef __attribute__((ext_vector_type(8))) short short8;   // 8 bf16 (4 VGPRs)
typedef __attribute__((ext_vector_type(4))) float floatx4;  // MFMA acc

__device__ __forceinline__ void fma4(float4& a, float s, const float4& v) {
    a.x = fmaf(s, v.x, a.x);
    a.y = fmaf(s, v.y, a.y);
    a.z = fmaf(s, v.z, a.z);
    a.w = fmaf(s, v.w, a.w);
}

// ---------------- zero init (ws is poisoned 0xAA every launch) ----------------
__global__ __launch_bounds__(THREADS) void zero_kernel(float* __restrict__ p, int n) {
    int i = blockIdx.x * THREADS + threadIdx.x;
    if (i < n) p[i] = 0.0f;   // bit pattern 0 also valid for u64 packed counters
}

// ---------------- fused histogram: one u64 atomic per edge, returns rank ----------------
__global__ __launch_bounds__(THREADS) void deg_count_kernel(
    const int* __restrict__ ei, const float* __restrict__ ew,
    unsigned long long* __restrict__ deg_cnt, int* __restrict__ rank, int E) {
    int e = blockIdx.x * THREADS + threadIdx.x;
    if (e >= E) return;
    int d = ei[E + e];                 // dst row of edge_index
    float w = ew[e];
    unsigned long long q = (unsigned long long)(w * 4294967296.0f);  // w in [0,1) -> 33 bits
    unsigned long long old = atomicAdd(&deg_cnt[d], (1ULL << CNT_SHIFT) | q);
    rank[e] = (int)(old >> CNT_SHIFT); // # prior edges to this dst = slot within CSR row
}

// ---------------- parallel scan stage 1: block sums + dinv ----------------
__global__ __launch_bounds__(THREADS) void scan_part1(
    const unsigned long long* __restrict__ deg_cnt,
    float* __restrict__ dinvv, int* __restrict__ partials, int n) {
    int t = threadIdx.x;
    int base = blockIdx.x * SCAN_CHUNK + t * 8;
    int s = 0;
#pragma unroll
    for (int i = 0; i < 8; ++i) {
        int idx = base + i;
        if (idx < n) {
            unsigned long long v = deg_cnt[idx];
            s += (int)(v >> CNT_SHIFT);
            float dg = (float)(v & DEG_MASK) * 0x1p-32f;   // un-fixed-point the weight sum
            dinvv[idx] = rsqrtf(dg + 1.0f);                // +1 = self-loop weight
        }
    }
    __shared__ int sm[THREADS];
    sm[t] = s;
    __syncthreads();
    for (int off = THREADS / 2; off > 0; off >>= 1) {
        if (t < off) sm[t] += sm[t + off];
        __syncthreads();
    }
    if (t == 0) partials[blockIdx.x] = sm[0];
}

// ---------------- parallel scan stage 2: exclusive scan of block partials ----------------
__global__ __launch_bounds__(1024) void scan_part2(int* __restrict__ partials, int nb) {
    __shared__ int s[1024];
    int t = threadIdx.x;
    int v = (t < nb) ? partials[t] : 0;
    s[t] = v;
    __syncthreads();
    for (int off = 1; off < 1024; off <<= 1) {
        int x = (t >= off) ? s[t - off] : 0;
        __syncthreads();
        s[t] += x;
        __syncthreads();
    }
    if (t < nb) partials[t] = s[t] - v;   // exclusive prefix
}

// ---------------- parallel scan stage 3: per-block local scan -> offs ----------------
__global__ __launch_bounds__(THREADS) void scan_part3(
    const unsigned long long* __restrict__ deg_cnt, const int* __restrict__ partials,
    int* __restrict__ offs, int n) {
    int t = threadIdx.x;
    int base = blockIdx.x * SCAN_CHUNK + t * 8;
    int loc[8];
    int s = 0;
#pragma unroll
    for (int i = 0; i < 8; ++i) {
        int idx = base + i;
        int c = (idx < n) ? (int)(deg_cnt[idx] >> CNT_SHIFT) : 0;
        loc[i] = c;
        s += c;
    }
    __shared__ int sm[THREADS];
    sm[t] = s;
    __syncthreads();
    for (int off = 1; off < THREADS; off <<= 1) {
        int x = (t >= off) ? sm[t - off] : 0;
        __syncthreads();
        sm[t] += x;
        __syncthreads();
    }
    int run = partials[blockIdx.x] + sm[t] - s;   // exclusive prefix of this thread's range
#pragma unroll
    for (int i = 0; i < 8; ++i) {
        int idx = base + i;
        if (idx < n) {
            offs[idx] = run;
            run += loc[i];
            if (idx == n - 1) offs[n] = run;
        }
    }
}

// ---------------- fill CSR: atomic-free (pos = offs[dst] + rank) ----------------
__global__ __launch_bounds__(THREADS) void fill_kernel(
    const int* __restrict__ ei, const float* __restrict__ ew,
    const float* __restrict__ dinvv, const int* __restrict__ offs,
    const int* __restrict__ rank, int2* __restrict__ csr, int E) {
    int e = blockIdx.x * THREADS + threadIdx.x;
    if (e >= E) return;
    int s = ei[e], d = ei[E + e];
    int pos = offs[d] + rank[e];
    csr[pos] = make_int2(s, __float_as_int(dinvv[s] * ew[e] * dinvv[d]));
}

// ---------------- W1 split+transpose: Wt_hi/lo[n=128][k=512] bf16 ----------------
__global__ __launch_bounds__(THREADS) void wsplit_kernel(
    const float* __restrict__ W, unsigned short* __restrict__ hi,
    unsigned short* __restrict__ lo) {
    int id = blockIdx.x * THREADS + threadIdx.x;   // 65536 = 512*128
    if (id >= 512 * 128) return;
    int k = id >> 7, n = id & 127;
    float v = W[id];                               // W[k][n]
    unsigned int b = __float_as_uint(v);
    unsigned short h = (unsigned short)(b >> 16);  // truncated hi bf16
    float fh = __uint_as_float(b & 0xFFFF0000u);
    unsigned short l = (unsigned short)(__float_as_uint(v - fh) >> 16);  // residual bf16
    hi[n * 512 + k] = h;
    lo[n * 512 + k] = l;
}

// ---------------- GEMM1 (MFMA): h0 = x @ W1, written to SLAB layout [8][M][16] ----------
// Split-bf16: x = xh + xl, w = wh + wl; acc += xh*wh + xh*wl + xl*wh (err ~2^-17).
__global__ __launch_bounds__(THREADS) void gemm1_mfma_kernel(
    const float* __restrict__ A, const unsigned short* __restrict__ Wth,
    const unsigned short* __restrict__ Wtl, float* __restrict__ C, int M) {
    __shared__ unsigned short As[2][64][72];    // [hi/lo][m][k]
    __shared__ unsigned short Bs[2][128][72];   // [hi/lo][n][k]
    int t = threadIdx.x;
    int brow0 = blockIdx.x * 64;
    int arow = t >> 2, akq = (t & 3) * 16;      // A: 64 rows x 4 chunks of 16 f32
    int bn = t >> 1, bkoff = (t & 1) * 32;      // B: 128 rows x 2 chunks of 32 bf16
    int wid = t >> 6, lane = t & 63;
    int wr = wid >> 1, wc = wid & 1;            // 2x2 wave grid
    int lm = lane & 15, lk = (lane >> 4) * 8;
    floatx4 acc[2][4];
#pragma unroll
    for (int i = 0; i < 2; i++)
#pragma unroll
        for (int j = 0; j < 4; j++) acc[i][j] = (floatx4)0.0f;

    int gr = brow0 + arow;
    for (int k0 = 0; k0 < 512; k0 += 64) {
        __syncthreads();
        {
            const float* ap = &A[(size_t)gr * 512 + k0 + akq];
#pragma unroll
            for (int i = 0; i < 4; ++i) {
                float4 v = (gr < M) ? *(const float4*)&ap[i * 4]
                                    : make_float4(0.f, 0.f, 0.f, 0.f);
                float e[4] = {v.x, v.y, v.z, v.w};
                ushort4 h4, l4;
                unsigned short* hp = (unsigned short*)&h4;
                unsigned short* lp = (unsigned short*)&l4;
#pragma unroll
                for (int c = 0; c < 4; ++c) {
                    unsigned int b = __float_as_uint(e[c]);
                    hp[c] = (unsigned short)(b >> 16);
                    float fh = __uint_as_float(b & 0xFFFF0000u);
                    lp[c] = (unsigned short)(__float_as_uint(e[c] - fh) >> 16);
                }
                *(ushort4*)&As[0][arow][akq + i * 4] = h4;
                *(ushort4*)&As[1][arow][akq + i * 4] = l4;
            }
        }
        {
            const unsigned short* bh = &Wth[(size_t)bn * 512 + k0 + bkoff];
            const unsigned short* bl = &Wtl[(size_t)bn * 512 + k0 + bkoff];
#pragma unroll
            for (int s = 0; s < 4; ++s) {
                *(float4*)&Bs[0][bn][bkoff + s * 8] = *(const float4*)&bh[s * 8];
                *(float4*)&Bs[1][bn][bkoff + s * 8] = *(const float4*)&bl[s * 8];
            }
        }
        __syncthreads();
#pragma unroll
        for (int kc = 0; kc < 2; ++kc) {
            int kb = kc * 32 + lk;
            short8 ah[2], al[2], bh[4], bl[4];
#pragma unroll
            for (int mf = 0; mf < 2; ++mf) {
                ah[mf] = *(const short8*)&As[0][wr * 32 + mf * 16 + lm][kb];
                al[mf] = *(const short8*)&As[1][wr * 32 + mf * 16 + lm][kb];
            }
#pragma unroll
            for (int nf = 0; nf < 4; ++nf) {
                bh[nf] = *(const short8*)&Bs[0][wc * 64 + nf * 16 + lm][kb];
                bl[nf] = *(const short8*)&Bs[1][wc * 64 + nf * 16 + lm][kb];
            }
#pragma unroll
            for (int mf = 0; mf < 2; ++mf)
#pragma unroll
                for (int nf = 0; nf < 4; ++nf) {
                    acc[mf][nf] = __builtin_amdgcn_mfma_f32_16x16x32_bf16(
                        ah[mf], bh[nf], acc[mf][nf], 0, 0, 0);
                    acc[mf][nf] = __builtin_amdgcn_mfma_f32_16x16x32_bf16(
                        ah[mf], bl[nf], acc[mf][nf], 0, 0, 0);
                    acc[mf][nf] = __builtin_amdgcn_mfma_f32_16x16x32_bf16(
                        al[mf], bh[nf], acc[mf][nf], 0, 0, 0);
                }
        }
    }
    // epilogue -> slab layout: C[col>>4][row][col&15]
#pragma unroll
    for (int mf = 0; mf < 2; ++mf) {
        int rbase = brow0 + wr * 32 + mf * 16 + (lane >> 4) * 4;
#pragma unroll
        for (int nf = 0; nf < 4; ++nf) {
            int col = wc * 64 + nf * 16 + lm;
            float* slab = C + (size_t)(col >> 4) * M * 16 + (col & 15);
#pragma unroll
            for (int r = 0; r < 4; ++r) {
                int g = rbase + r;
                if (g < M) slab[(size_t)g * 16] = acc[mf][nf][r];
            }
        }
    }
}

// ---------------- SpMM on slab layout, XCD-pinned ----------------
// slice = blockIdx%8 -> each slab (3.2MB contiguous) pinned to one XCD's L2.
// 16 nodes per wave; 4 lanes/node each handling 4 channels (float4 gathers).
__global__ __launch_bounds__(THREADS) void spmm_slab_kernel(
    const float* __restrict__ feat, const float* __restrict__ dinvv,
    const int* __restrict__ offs, const int2* __restrict__ csr,
    const float* __restrict__ bias, float* __restrict__ out, int n, int do_relu) {
    int slice = blockIdx.x & (NSLICE - 1);
    int chunk = blockIdx.x / NSLICE;
    int t = threadIdx.x;
    int wave = t >> 6, lane = t & 63;
    int node = chunk * NPB + wave * 16 + (lane >> 2);
    int lidx = lane & 3;                         // 4 channels each
    bool valid = node < n;
    int nd = valid ? node : (n - 1);
    const float* __restrict__ fb = feat + (size_t)slice * n * 16 + lidx * 4;

    float di = dinvv[nd];
    float sw = di * di;
    float4 acc = *(const float4*)&fb[(size_t)nd * 16];
    acc.x *= sw; acc.y *= sw; acc.z *= sw; acc.w *= sw;

    int j0 = offs[nd];
    int m = valid ? (offs[nd + 1] - j0) : 0;
    const int2* __restrict__ cp = csr + ((m > 0) ? j0 : 0);
    // wave-max degree (node id varies on lane bits 2..5)
    int mm = m;
    mm = max(mm, __shfl_xor(mm, 4));
    mm = max(mm, __shfl_xor(mm, 8));
    mm = max(mm, __shfl_xor(mm, 16));
    mm = max(mm, __shfl_xor(mm, 32));

    int2 eA[D], eB[D];
    float wA[D], wB[D];
    float4 vA[D], vB[D];
#define LD_E(jj) cp[((jj) < m) ? (jj) : 0]
#define MASK_W(jj, e) (((jj) < m) ? __int_as_float((e).y) : 0.0f)

#pragma unroll
    for (int i = 0; i < D; ++i) eA[i] = LD_E(i);
#pragma unroll
    for (int i = 0; i < D; ++i) eB[i] = LD_E(D + i);
#pragma unroll
    for (int i = 0; i < D; ++i) {
        wA[i] = MASK_W(i, eA[i]);
        vA[i] = *(const float4*)&fb[(size_t)eA[i].x * 16];
    }

    int g = 0;
    for (; g + 4 * D <= mm; g += 2 * D) {
#pragma unroll
        for (int i = 0; i < D; ++i) eA[i] = LD_E(g + 2 * D + i);
#pragma unroll
        for (int i = 0; i < D; ++i) {
            wB[i] = MASK_W(g + D + i, eB[i]);
            vB[i] = *(const float4*)&fb[(size_t)eB[i].x * 16];
        }
#pragma unroll
        for (int i = 0; i < D; ++i) fma4(acc, wA[i], vA[i]);
#pragma unroll
        for (int i = 0; i < D; ++i) eB[i] = LD_E(g + 3 * D + i);
#pragma unroll
        for (int i = 0; i < D; ++i) {
            wA[i] = MASK_W(g + 2 * D + i, eA[i]);
            vA[i] = *(const float4*)&fb[(size_t)eA[i].x * 16];
        }
#pragma unroll
        for (int i = 0; i < D; ++i) fma4(acc, wB[i], vB[i]);
    }
#pragma unroll
    for (int i = 0; i < D; ++i) if (g + i < mm) fma4(acc, wA[i], vA[i]);
    g += D;
#pragma unroll
    for (int i = 0; i < D; ++i) if (g + i < mm) {
        float w = MASK_W(g + i, eB[i]);
        float4 v = *(const float4*)&fb[(size_t)eB[i].x * 16];
        fma4(acc, w, v);
    }
    g += D;
    for (; g < mm; ++g) {
        int2 e = LD_E(g);
        float w = MASK_W(g, e);
        float4 v = *(const float4*)&fb[(size_t)e.x * 16];
        fma4(acc, w, v);
    }
#undef LD_E
#undef MASK_W

    if (bias) {
        float4 b = *(const float4*)&bias[slice * 16 + lidx * 4];
        acc.x += b.x; acc.y += b.y; acc.z += b.z; acc.w += b.w;
    }
    if (do_relu) {
        acc.x = fmaxf(acc.x, 0.0f); acc.y = fmaxf(acc.y, 0.0f);
        acc.z = fmaxf(acc.z, 0.0f); acc.w = fmaxf(acc.w, 0.0f);
    }
    if (valid)
        *(float4*)&out[(size_t)slice * n * 16 + (size_t)node * 16 + lidx * 4] = acc;
}

// ---------------- GEMM23: [mean|logstd] = agg2(slab layout) @ [W2|W3] + [b2|b3] ------
__global__ __launch_bounds__(THREADS) void gemm23_kernel(
    const float* __restrict__ A, const float* __restrict__ W2,
    const float* __restrict__ W3, const float* __restrict__ b2,
    const float* __restrict__ b3, float* __restrict__ outm,
    float* __restrict__ outl, int M) {
    __shared__ float As[16][68];
    __shared__ float Bs[16][128];
    int t = threadIdx.x;
    int ty = t >> 4, tx = t & 15;
    int brow0 = blockIdx.x * 64;
    int arow = t >> 2, aq = t & 3;
    int bkr = t >> 5, bcol = (t & 31) * 4;
    float acc[4][8];
#pragma unroll
    for (int i = 0; i < 4; i++)
#pragma unroll
        for (int j = 0; j < 8; j++) acc[i][j] = 0.0f;
    int gr = brow0 + arow;
    const float4 z4 = make_float4(0.f, 0.f, 0.f, 0.f);
    for (int k0 = 0; k0 < 128; k0 += 16) {
        // A is in slab layout: element (gr, k) at A[(k>>4)*M*16 + gr*16 + (k&15)]
        float4 av = (gr < M)
            ? *(const float4*)&A[((size_t)(k0 >> 4) * M + gr) * 16 + aq * 4]
            : z4;
        int k1 = k0 + bkr, k2 = k0 + bkr + 8;
        float4 b0 = (bcol < 64) ? *(const float4*)&W2[(size_t)k1 * 64 + bcol]
                                : *(const float4*)&W3[(size_t)k1 * 64 + bcol - 64];
        float4 b1 = (bcol < 64) ? *(const float4*)&W2[(size_t)k2 * 64 + bcol]
                                : *(const float4*)&W3[(size_t)k2 * 64 + bcol - 64];
        __syncthreads();
        As[aq * 4 + 0][arow] = av.x;
        As[aq * 4 + 1][arow] = av.y;
        As[aq * 4 + 2][arow] = av.z;
        As[aq * 4 + 3][arow] = av.w;
        *(float4*)&Bs[bkr][bcol] = b0;
        *(float4*)&Bs[bkr + 8][bcol] = b1;
        __syncthreads();
#pragma unroll
        for (int kk = 0; kk < 16; ++kk) {
            float4 a = *(const float4*)&As[kk][ty * 4];
            float4 p0 = *(const float4*)&Bs[kk][tx * 8];
            float4 p1 = *(const float4*)&Bs[kk][tx * 8 + 4];
            float av_[4] = {a.x, a.y, a.z, a.w};
            float bv_[8] = {p0.x, p0.y, p0.z, p0.w, p1.x, p1.y, p1.z, p1.w};
#pragma unroll
            for (int i = 0; i < 4; i++)
#pragma unroll
                for (int j = 0; j < 8; j++)
                    acc[i][j] = fmaf(av_[i], bv_[j], acc[i][j]);
        }
    }
    bool is_mean = (tx < 8);
    int c = is_mean ? tx * 8 : tx * 8 - 64;
    const float* bb = is_mean ? b2 : b3;
    float* op = is_mean ? outm : outl;
    float4 bias0 = *(const float4*)&bb[c];
    float4 bias1 = *(const float4*)&bb[c + 4];
#pragma unroll
    for (int i = 0; i < 4; i++) {
        int r = brow0 + ty * 4 + i;
        if (r < M) {
            *(float4*)&op[(size_t)r * 64 + c] =
                make_float4(acc[i][0] + bias0.x, acc[i][1] + bias0.y,
                            acc[i][2] + bias0.z, acc[i][3] + bias0.w);
            *(float4*)&op[(size_t)r * 64 + c + 4] =
                make_float4(acc[i][4] + bias1.x, acc[i][5] + bias1.y,
                            acc[i][6] + bias1.z, acc[i][7] + bias1.w);
        }
    }
}

extern "C" void kernel_launch(void* const* d_in, const int* in_sizes, int n_in,
                              void* d_out, int out_size, void* d_ws, size_t ws_size,
                              hipStream_t stream) {
    const float* x  = (const float*)d_in[0];
    const int*   ei = (const int*)d_in[1];
    const float* ew = (const float*)d_in[2];
    const float* W1 = (const float*)d_in[3];
    const float* b1 = (const float*)d_in[4];
    const float* W2 = (const float*)d_in[5];
    const float* b2 = (const float*)d_in[6];
    const float* W3 = (const float*)d_in[7];
    const float* b3 = (const float*)d_in[8];

    const int n = in_sizes[0] / 512;   // 50000
    const int E = in_sizes[2];         // 1600000
    const int nb_scan = (n + SCAN_CHUNK - 1) / SCAN_CHUNK;   // 25

    char* p = (char*)d_ws;
    auto alloc = [&](size_t bytes) {
        char* q = p;
        p += (bytes + 511) & ~(size_t)511;
        return q;
    };
    unsigned long long* deg_cnt = (unsigned long long*)alloc((size_t)n * 8);
    float* dinvv  = (float*)alloc((size_t)n * 4);
    int*   offs   = (int*)alloc((size_t)(n + 1) * 4);
    int*   rank   = (int*)alloc((size_t)E * 4);
    int*   partials = (int*)alloc((size_t)nb_scan * 4);
    int2*  csr    = (int2*)alloc((size_t)E * 8);
    unsigned short* Wth = (unsigned short*)alloc((size_t)512 * 128 * 2);
    unsigned short* Wtl = (unsigned short*)alloc((size_t)512 * 128 * 2);
    float* h0     = (float*)alloc((size_t)n * 128 * 4);  // slab layout, reused as agg2
    float* hb     = (float*)alloc((size_t)n * 128 * 4);  // slab layout
    float* agg2   = h0;

    float* outm = (float*)d_out;
    float* outl = outm + (size_t)n * 64;

    const int spmm_grid = ((n + NPB - 1) / NPB) * NSLICE;   // 782 * 8 = 6256

    zero_kernel<<<(2 * n + THREADS - 1) / THREADS, THREADS, 0, stream>>>((float*)deg_cnt, 2 * n);
    deg_count_kernel<<<(E + THREADS - 1) / THREADS, THREADS, 0, stream>>>(ei, ew, deg_cnt, rank, E);
    scan_part1<<<nb_scan, THREADS, 0, stream>>>(deg_cnt, dinvv, partials, n);
    scan_part2<<<1, 1024, 0, stream>>>(partials, nb_scan);
    scan_part3<<<nb_scan, THREADS, 0, stream>>>(deg_cnt, partials, offs, n);
    fill_kernel<<<(E + THREADS - 1) / THREADS, THREADS, 0, stream>>>(ei, ew, dinvv, offs,
                                                                     rank, csr, E);
    wsplit_kernel<<<(512 * 128 + THREADS - 1) / THREADS, THREADS, 0, stream>>>(W1, Wth, Wtl);
    gemm1_mfma_kernel<<<(n + 63) / 64, THREADS, 0, stream>>>(x, Wth, Wtl, h0, n);
    spmm_slab_kernel<<<spmm_grid, THREADS, 0, stream>>>(h0, dinvv, offs, csr, b1, hb, n, 1);
    spmm_slab_kernel<<<spmm_grid, THREADS, 0, stream>>>(hb, dinvv, offs, csr, nullptr, agg2, n, 0);
    gemm23_kernel<<<(n + 63) / 64, THREADS, 0, stream>>>(agg2, W2, W3, b2, b3, outm, outl, n);
}

// Round 10
// 481.343 us; speedup vs baseline: 1.4673x; 1.3110x over previous
//
#include <hip/hip_runtime.h>

// GCN encoder: h = relu(A_norm @ (x@W1) + b1); mean = (A_norm@h)@W2+b2; logstd = (A_norm@h)@W3+b3
// R2: 3-stage parallel scan. R3/R4: spmm ping-pong pipeline (161->108us).
// R5: packed u64 atomic histogram -> atomic-free fill. R6: split-bf16 MFMA gemm1.
// R7/R9: channel-sliced / slab spmm experiments: slab+XCD-pin fixed FETCH (453->198MB)
//     but structural overhead (wave-max-degree inflation, 8x slice loops) cost more than
//     the residency saved (136us > R6's 108us). REVERTED to wave-per-node spmm.
// R10: halve spmm gather bytes instead: bf16 feature storage (h0, hb as bf16[n][128];
//     256B/row gathers, 1 dword/lane). Error ~1e-4 at outputs (aggregation weights
//     contract quant noise). agg2 stays f32; gemm23 back to row-major f32 reader.

#define THREADS 256
#define SCAN_CHUNK 2048   // elements per block in the scan kernels (256 thr x 8)
#define D 4               // spmm pipeline group size (2 groups in flight = 8 feat loads)

#define DEG_MASK ((1ULL << 40) - 1)
#define CNT_SHIFT 40

typedef __attribute__((ext_vector_type(8))) short short8;   // 8 bf16 (4 VGPRs)
typedef __attribute__((ext_vector_type(4))) float floatx4;  // MFMA acc

__device__ __forceinline__ unsigned short f32_to_bf16(float v) {
    return (unsigned short)((__float_as_uint(v) + 0x8000u) >> 16);  // round-half-up
}

// ---------------- zero init (ws is poisoned 0xAA every launch) ----------------
__global__ __launch_bounds__(THREADS) void zero_kernel(float* __restrict__ p, int n) {
    int i = blockIdx.x * THREADS + threadIdx.x;
    if (i < n) p[i] = 0.0f;   // bit pattern 0 also valid for u64 packed counters
}

// ---------------- fused histogram: one u64 atomic per edge, returns rank ----------------
__global__ __launch_bounds__(THREADS) void deg_count_kernel(
    const int* __restrict__ ei, const float* __restrict__ ew,
    unsigned long long* __restrict__ deg_cnt, int* __restrict__ rank, int E) {
    int e = blockIdx.x * THREADS + threadIdx.x;
    if (e >= E) return;
    int d = ei[E + e];                 // dst row of edge_index
    float w = ew[e];
    unsigned long long q = (unsigned long long)(w * 4294967296.0f);  // w in [0,1) -> 33 bits
    unsigned long long old = atomicAdd(&deg_cnt[d], (1ULL << CNT_SHIFT) | q);
    rank[e] = (int)(old >> CNT_SHIFT); // # prior edges to this dst = slot within CSR row
}

// ---------------- parallel scan stage 1: block sums + dinv ----------------
__global__ __launch_bounds__(THREADS) void scan_part1(
    const unsigned long long* __restrict__ deg_cnt,
    float* __restrict__ dinvv, int* __restrict__ partials, int n) {
    int t = threadIdx.x;
    int base = blockIdx.x * SCAN_CHUNK + t * 8;
    int s = 0;
#pragma unroll
    for (int i = 0; i < 8; ++i) {
        int idx = base + i;
        if (idx < n) {
            unsigned long long v = deg_cnt[idx];
            s += (int)(v >> CNT_SHIFT);
            float dg = (float)(v & DEG_MASK) * 0x1p-32f;   // un-fixed-point the weight sum
            dinvv[idx] = rsqrtf(dg + 1.0f);                // +1 = self-loop weight
        }
    }
    __shared__ int sm[THREADS];
    sm[t] = s;
    __syncthreads();
    for (int off = THREADS / 2; off > 0; off >>= 1) {
        if (t < off) sm[t] += sm[t + off];
        __syncthreads();
    }
    if (t == 0) partials[blockIdx.x] = sm[0];
}

// ---------------- parallel scan stage 2: exclusive scan of block partials ----------------
__global__ __launch_bounds__(1024) void scan_part2(int* __restrict__ partials, int nb) {
    __shared__ int s[1024];
    int t = threadIdx.x;
    int v = (t < nb) ? partials[t] : 0;
    s[t] = v;
    __syncthreads();
    for (int off = 1; off < 1024; off <<= 1) {
        int x = (t >= off) ? s[t - off] : 0;
        __syncthreads();
        s[t] += x;
        __syncthreads();
    }
    if (t < nb) partials[t] = s[t] - v;   // exclusive prefix
}

// ---------------- parallel scan stage 3: per-block local scan -> offs ----------------
__global__ __launch_bounds__(THREADS) void scan_part3(
    const unsigned long long* __restrict__ deg_cnt, const int* __restrict__ partials,
    int* __restrict__ offs, int n) {
    int t = threadIdx.x;
    int base = blockIdx.x * SCAN_CHUNK + t * 8;
    int loc[8];
    int s = 0;
#pragma unroll
    for (int i = 0; i < 8; ++i) {
        int idx = base + i;
        int c = (idx < n) ? (int)(deg_cnt[idx] >> CNT_SHIFT) : 0;
        loc[i] = c;
        s += c;
    }
    __shared__ int sm[THREADS];
    sm[t] = s;
    __syncthreads();
    for (int off = 1; off < THREADS; off <<= 1) {
        int x = (t >= off) ? sm[t - off] : 0;
        __syncthreads();
        sm[t] += x;
        __syncthreads();
    }
    int run = partials[blockIdx.x] + sm[t] - s;   // exclusive prefix of this thread's range
#pragma unroll
    for (int i = 0; i < 8; ++i) {
        int idx = base + i;
        if (idx < n) {
            offs[idx] = run;
            run += loc[i];
            if (idx == n - 1) offs[n] = run;
        }
    }
}

// ---------------- fill CSR: atomic-free (pos = offs[dst] + rank) ----------------
__global__ __launch_bounds__(THREADS) void fill_kernel(
    const int* __restrict__ ei, const float* __restrict__ ew,
    const float* __restrict__ dinvv, const int* __restrict__ offs,
    const int* __restrict__ rank, int2* __restrict__ csr, int E) {
    int e = blockIdx.x * THREADS + threadIdx.x;
    if (e >= E) return;
    int s = ei[e], d = ei[E + e];
    int pos = offs[d] + rank[e];
    csr[pos] = make_int2(s, __float_as_int(dinvv[s] * ew[e] * dinvv[d]));
}

// ---------------- W1 split+transpose: Wt_hi/lo[n=128][k=512] bf16 ----------------
__global__ __launch_bounds__(THREADS) void wsplit_kernel(
    const float* __restrict__ W, unsigned short* __restrict__ hi,
    unsigned short* __restrict__ lo) {
    int id = blockIdx.x * THREADS + threadIdx.x;   // 65536 = 512*128
    if (id >= 512 * 128) return;
    int k = id >> 7, n = id & 127;
    float v = W[id];                               // W[k][n]
    unsigned int b = __float_as_uint(v);
    unsigned short h = (unsigned short)(b >> 16);  // truncated hi bf16
    float fh = __uint_as_float(b & 0xFFFF0000u);
    unsigned short l = (unsigned short)(__float_as_uint(v - fh) >> 16);  // residual bf16
    hi[n * 512 + k] = h;
    lo[n * 512 + k] = l;
}

// ---------------- GEMM1 (MFMA): h0[M,128] (bf16) = x[M,512] @ W1[512,128] ----------
// Split-bf16: x = xh + xl, w = wh + wl; acc += xh*wh + xh*wl + xl*wh (err ~2^-17).
// Output quantized to bf16 (spmm gathers at half the bytes).
__global__ __launch_bounds__(THREADS) void gemm1_mfma_kernel(
    const float* __restrict__ A, const unsigned short* __restrict__ Wth,
    const unsigned short* __restrict__ Wtl, unsigned short* __restrict__ C, int M) {
    __shared__ unsigned short As[2][64][72];    // [hi/lo][m][k]
    __shared__ unsigned short Bs[2][128][72];   // [hi/lo][n][k]
    int t = threadIdx.x;
    int brow0 = blockIdx.x * 64;
    int arow = t >> 2, akq = (t & 3) * 16;      // A: 64 rows x 4 chunks of 16 f32
    int bn = t >> 1, bkoff = (t & 1) * 32;      // B: 128 rows x 2 chunks of 32 bf16
    int wid = t >> 6, lane = t & 63;
    int wr = wid >> 1, wc = wid & 1;            // 2x2 wave grid
    int lm = lane & 15, lk = (lane >> 4) * 8;
    floatx4 acc[2][4];
#pragma unroll
    for (int i = 0; i < 2; i++)
#pragma unroll
        for (int j = 0; j < 4; j++) acc[i][j] = (floatx4)0.0f;

    int gr = brow0 + arow;
    for (int k0 = 0; k0 < 512; k0 += 64) {
        __syncthreads();
        {
            const float* ap = &A[(size_t)gr * 512 + k0 + akq];
#pragma unroll
            for (int i = 0; i < 4; ++i) {
                float4 v = (gr < M) ? *(const float4*)&ap[i * 4]
                                    : make_float4(0.f, 0.f, 0.f, 0.f);
                float e[4] = {v.x, v.y, v.z, v.w};
                ushort4 h4, l4;
                unsigned short* hp = (unsigned short*)&h4;
                unsigned short* lp = (unsigned short*)&l4;
#pragma unroll
                for (int c = 0; c < 4; ++c) {
                    unsigned int b = __float_as_uint(e[c]);
                    hp[c] = (unsigned short)(b >> 16);
                    float fh = __uint_as_float(b & 0xFFFF0000u);
                    lp[c] = (unsigned short)(__float_as_uint(e[c] - fh) >> 16);
                }
                *(ushort4*)&As[0][arow][akq + i * 4] = h4;
                *(ushort4*)&As[1][arow][akq + i * 4] = l4;
            }
        }
        {
            const unsigned short* bh = &Wth[(size_t)bn * 512 + k0 + bkoff];
            const unsigned short* bl = &Wtl[(size_t)bn * 512 + k0 + bkoff];
#pragma unroll
            for (int s = 0; s < 4; ++s) {
                *(float4*)&Bs[0][bn][bkoff + s * 8] = *(const float4*)&bh[s * 8];
                *(float4*)&Bs[1][bn][bkoff + s * 8] = *(const float4*)&bl[s * 8];
            }
        }
        __syncthreads();
#pragma unroll
        for (int kc = 0; kc < 2; ++kc) {
            int kb = kc * 32 + lk;
            short8 ah[2], al[2], bh[4], bl[4];
#pragma unroll
            for (int mf = 0; mf < 2; ++mf) {
                ah[mf] = *(const short8*)&As[0][wr * 32 + mf * 16 + lm][kb];
                al[mf] = *(const short8*)&As[1][wr * 32 + mf * 16 + lm][kb];
            }
#pragma unroll
            for (int nf = 0; nf < 4; ++nf) {
                bh[nf] = *(const short8*)&Bs[0][wc * 64 + nf * 16 + lm][kb];
                bl[nf] = *(const short8*)&Bs[1][wc * 64 + nf * 16 + lm][kb];
            }
#pragma unroll
            for (int mf = 0; mf < 2; ++mf)
#pragma unroll
                for (int nf = 0; nf < 4; ++nf) {
                    acc[mf][nf] = __builtin_amdgcn_mfma_f32_16x16x32_bf16(
                        ah[mf], bh[nf], acc[mf][nf], 0, 0, 0);
                    acc[mf][nf] = __builtin_amdgcn_mfma_f32_16x16x32_bf16(
                        ah[mf], bl[nf], acc[mf][nf], 0, 0, 0);
                    acc[mf][nf] = __builtin_amdgcn_mfma_f32_16x16x32_bf16(
                        al[mf], bh[nf], acc[mf][nf], 0, 0, 0);
                }
        }
    }
    // epilogue: C/D layout col = lane&15, row = (lane>>4)*4 + reg; bf16 row-major out
#pragma unroll
    for (int mf = 0; mf < 2; ++mf) {
        int rbase = brow0 + wr * 32 + mf * 16 + (lane >> 4) * 4;
#pragma unroll
        for (int nf = 0; nf < 4; ++nf) {
            int col = wc * 64 + nf * 16 + lm;
#pragma unroll
            for (int r = 0; r < 4; ++r) {
                int g = rbase + r;
                if (g < M) C[(size_t)g * 128 + col] = f32_to_bf16(acc[mf][nf][r]);
            }
        }
    }
}

// ---------------- SpMM (bf16 gather): out[d,:] = sum_e w_e*feat[src_e,:] + dinv^2*feat[d,:]
// one wave per dst node; 2 channels per lane (1 dword of 2 bf16); software-pipelined:
// csr scalar path (readfirstlane'd dst), feat loads ping-pong with 2 groups of D in flight.
// Output: bf16 (outb) for next gather, or f32 (outf) for gemm23.
__global__ __launch_bounds__(THREADS) void spmm_bf16_kernel(
    const unsigned short* __restrict__ feat, const float* __restrict__ dinvv,
    const int* __restrict__ offs, const int2* __restrict__ csr,
    const float* __restrict__ bias, unsigned short* __restrict__ outb,
    float* __restrict__ outf, int n, int do_relu) {
    int gw = (blockIdx.x * THREADS + threadIdx.x) >> 6;
    int lane = threadIdx.x & 63;
    if (gw >= n) return;
    const int d = __builtin_amdgcn_readfirstlane(gw);   // wave-uniform -> SALU/s_load path
    float di = dinvv[d];
    float sw = di * di;                                 // self-loop norm = 1/deg
    const unsigned int* __restrict__ f1 = (const unsigned int*)feat + lane;  // word per 2ch
    unsigned int sv = f1[(size_t)d * 64];
    float2 acc;
    acc.x = __uint_as_float(sv << 16) * sw;
    acc.y = __uint_as_float(sv & 0xFFFF0000u) * sw;
    int j0 = offs[d];
    int m = offs[d + 1] - j0;
    const int2* __restrict__ cp = csr + j0;

    int2 eA[D], eB[D];
    float wA[D], wB[D];
    unsigned int vA[D], vB[D];

    // prologue: csr groups 0 and 1; feat group 0 in flight
#pragma unroll
    for (int i = 0; i < D; ++i) if (i < m) eA[i] = cp[i];
#pragma unroll
    for (int i = 0; i < D; ++i) if (D + i < m) eB[i] = cp[D + i];
#pragma unroll
    for (int i = 0; i < D; ++i) if (i < m) {
        wA[i] = __int_as_float(eA[i].y);
        vA[i] = f1[(size_t)eA[i].x * 64];
    }

    int g = 0;
    for (; g + 4 * D <= m; g += 2 * D) {
        // half 1: consume group g (vA/wA); eB holds csr(g+D)
#pragma unroll
        for (int i = 0; i < D; ++i) eA[i] = cp[g + 2 * D + i];       // csr for g+2D
#pragma unroll
        for (int i = 0; i < D; ++i) {
            wB[i] = __int_as_float(eB[i].y);
            vB[i] = f1[(size_t)eB[i].x * 64];                        // feat for g+D
        }
#pragma unroll
        for (int i = 0; i < D; ++i) {
            acc.x = fmaf(wA[i], __uint_as_float(vA[i] << 16), acc.x);
            acc.y = fmaf(wA[i], __uint_as_float(vA[i] & 0xFFFF0000u), acc.y);
        }
        // half 2: consume group g+D (vB/wB); eA holds csr(g+2D)
#pragma unroll
        for (int i = 0; i < D; ++i) eB[i] = cp[g + 3 * D + i];       // csr for g+3D
#pragma unroll
        for (int i = 0; i < D; ++i) {
            wA[i] = __int_as_float(eA[i].y);
            vA[i] = f1[(size_t)eA[i].x * 64];                        // feat for g+2D
        }
#pragma unroll
        for (int i = 0; i < D; ++i) {
            acc.x = fmaf(wB[i], __uint_as_float(vB[i] << 16), acc.x);
            acc.y = fmaf(wB[i], __uint_as_float(vB[i] & 0xFFFF0000u), acc.y);
        }
    }
    // epilogue: group g in flight (vA), csr for group g+D resident in eB (guarded)
#pragma unroll
    for (int i = 0; i < D; ++i) if (g + i < m) {
        acc.x = fmaf(wA[i], __uint_as_float(vA[i] << 16), acc.x);
        acc.y = fmaf(wA[i], __uint_as_float(vA[i] & 0xFFFF0000u), acc.y);
    }
    g += D;
#pragma unroll
    for (int i = 0; i < D; ++i) if (g + i < m) {
        float w = __int_as_float(eB[i].y);
        unsigned int v = f1[(size_t)eB[i].x * 64];
        acc.x = fmaf(w, __uint_as_float(v << 16), acc.x);
        acc.y = fmaf(w, __uint_as_float(v & 0xFFFF0000u), acc.y);
    }
    g += D;
    for (; g < m; ++g) {
        int2 e = cp[g];
        float w = __int_as_float(e.y);
        unsigned int v = f1[(size_t)e.x * 64];
        acc.x = fmaf(w, __uint_as_float(v << 16), acc.x);
        acc.y = fmaf(w, __uint_as_float(v & 0xFFFF0000u), acc.y);
    }

    if (bias) {
        float2 b = *(const float2*)&bias[lane * 2];
        acc.x += b.x;
        acc.y += b.y;
    }
    if (do_relu) {
        acc.x = fmaxf(acc.x, 0.0f);
        acc.y = fmaxf(acc.y, 0.0f);
    }
    if (outb) {
        unsigned int lo = (__float_as_uint(acc.x) + 0x8000u) >> 16;
        unsigned int hi = (__float_as_uint(acc.y) + 0x8000u) & 0xFFFF0000u;
        ((unsigned int*)outb)[(size_t)d * 64 + lane] = hi | lo;
    } else {
        ((float2*)outf)[(size_t)d * 64 + lane] = acc;
    }
}

// ---------------- GEMM23: [mean|logstd] = agg2[M,128] @ [W2|W3][128,128] + [b2|b3] ------
__global__ __launch_bounds__(THREADS) void gemm23_kernel(
    const float* __restrict__ A, const float* __restrict__ W2,
    const float* __restrict__ W3, const float* __restrict__ b2,
    const float* __restrict__ b3, float* __restrict__ outm,
    float* __restrict__ outl, int M) {
    __shared__ float As[16][68];
    __shared__ float Bs[16][128];
    int t = threadIdx.x;
    int ty = t >> 4, tx = t & 15;
    int brow0 = blockIdx.x * 64;
    int arow = t >> 2, aq = t & 3;
    int bkr = t >> 5, bcol = (t & 31) * 4;
    float acc[4][8];
#pragma unroll
    for (int i = 0; i < 4; i++)
#pragma unroll
        for (int j = 0; j < 8; j++) acc[i][j] = 0.0f;
    int gr = brow0 + arow;
    const float4 z4 = make_float4(0.f, 0.f, 0.f, 0.f);
    for (int k0 = 0; k0 < 128; k0 += 16) {
        float4 av = (gr < M) ? *(const float4*)&A[(size_t)gr * 128 + k0 + aq * 4] : z4;
        int k1 = k0 + bkr, k2 = k0 + bkr + 8;
        float4 b0 = (bcol < 64) ? *(const float4*)&W2[(size_t)k1 * 64 + bcol]
                                : *(const float4*)&W3[(size_t)k1 * 64 + bcol - 64];
        float4 b1 = (bcol < 64) ? *(const float4*)&W2[(size_t)k2 * 64 + bcol]
                                : *(const float4*)&W3[(size_t)k2 * 64 + bcol - 64];
        __syncthreads();
        As[aq * 4 + 0][arow] = av.x;
        As[aq * 4 + 1][arow] = av.y;
        As[aq * 4 + 2][arow] = av.z;
        As[aq * 4 + 3][arow] = av.w;
        *(float4*)&Bs[bkr][bcol] = b0;
        *(float4*)&Bs[bkr + 8][bcol] = b1;
        __syncthreads();
#pragma unroll
        for (int kk = 0; kk < 16; ++kk) {
            float4 a = *(const float4*)&As[kk][ty * 4];
            float4 p0 = *(const float4*)&Bs[kk][tx * 8];
            float4 p1 = *(const float4*)&Bs[kk][tx * 8 + 4];
            float av_[4] = {a.x, a.y, a.z, a.w};
            float bv_[8] = {p0.x, p0.y, p0.z, p0.w, p1.x, p1.y, p1.z, p1.w};
#pragma unroll
            for (int i = 0; i < 4; i++)
#pragma unroll
                for (int j = 0; j < 8; j++)
                    acc[i][j] = fmaf(av_[i], bv_[j], acc[i][j]);
        }
    }
    bool is_mean = (tx < 8);
    int c = is_mean ? tx * 8 : tx * 8 - 64;
    const float* bb = is_mean ? b2 : b3;
    float* op = is_mean ? outm : outl;
    float4 bias0 = *(const float4*)&bb[c];
    float4 bias1 = *(const float4*)&bb[c + 4];
#pragma unroll
    for (int i = 0; i < 4; i++) {
        int r = brow0 + ty * 4 + i;
        if (r < M) {
            *(float4*)&op[(size_t)r * 64 + c] =
                make_float4(acc[i][0] + bias0.x, acc[i][1] + bias0.y,
                            acc[i][2] + bias0.z, acc[i][3] + bias0.w);
            *(float4*)&op[(size_t)r * 64 + c + 4] =
                make_float4(acc[i][4] + bias1.x, acc[i][5] + bias1.y,
                            acc[i][6] + bias1.z, acc[i][7] + bias1.w);
        }
    }
}

extern "C" void kernel_launch(void* const* d_in, const int* in_sizes, int n_in,
                              void* d_out, int out_size, void* d_ws, size_t ws_size,
                              hipStream_t stream) {
    const float* x  = (const float*)d_in[0];
    const int*   ei = (const int*)d_in[1];
    const float* ew = (const float*)d_in[2];
    const float* W1 = (const float*)d_in[3];
    const float* b1 = (const float*)d_in[4];
    const float* W2 = (const float*)d_in[5];
    const float* b2 = (const float*)d_in[6];
    const float* W3 = (const float*)d_in[7];
    const float* b3 = (const float*)d_in[8];

    const int n = in_sizes[0] / 512;   // 50000
    const int E = in_sizes[2];         // 1600000
    const int nb_scan = (n + SCAN_CHUNK - 1) / SCAN_CHUNK;   // 25

    char* p = (char*)d_ws;
    auto alloc = [&](size_t bytes) {
        char* q = p;
        p += (bytes + 511) & ~(size_t)511;
        return q;
    };
    unsigned long long* deg_cnt = (unsigned long long*)alloc((size_t)n * 8);
    float* dinvv  = (float*)alloc((size_t)n * 4);
    int*   offs   = (int*)alloc((size_t)(n + 1) * 4);
    int*   rank   = (int*)alloc((size_t)E * 4);
    int*   partials = (int*)alloc((size_t)nb_scan * 4);
    int2*  csr    = (int2*)alloc((size_t)E * 8);
    unsigned short* Wth = (unsigned short*)alloc((size_t)512 * 128 * 2);
    unsigned short* Wtl = (unsigned short*)alloc((size_t)512 * 128 * 2);
    unsigned short* h0b = (unsigned short*)alloc((size_t)n * 128 * 2);  // bf16 x@W1
    unsigned short* hbb = (unsigned short*)alloc((size_t)n * 128 * 2);  // bf16 relu'd hidden
    float* agg2   = (float*)alloc((size_t)n * 128 * 4);                 // f32 A@hb

    float* outm = (float*)d_out;
    float* outl = outm + (size_t)n * 64;

    zero_kernel<<<(2 * n + THREADS - 1) / THREADS, THREADS, 0, stream>>>((float*)deg_cnt, 2 * n);
    deg_count_kernel<<<(E + THREADS - 1) / THREADS, THREADS, 0, stream>>>(ei, ew, deg_cnt, rank, E);
    scan_part1<<<nb_scan, THREADS, 0, stream>>>(deg_cnt, dinvv, partials, n);
    scan_part2<<<1, 1024, 0, stream>>>(partials, nb_scan);
    scan_part3<<<nb_scan, THREADS, 0, stream>>>(deg_cnt, partials, offs, n);
    fill_kernel<<<(E + THREADS - 1) / THREADS, THREADS, 0, stream>>>(ei, ew, dinvv, offs,
                                                                     rank, csr, E);
    wsplit_kernel<<<(512 * 128 + THREADS - 1) / THREADS, THREADS, 0, stream>>>(W1, Wth, Wtl);
    gemm1_mfma_kernel<<<(n + 63) / 64, THREADS, 0, stream>>>(x, Wth, Wtl, h0b, n);
    spmm_bf16_kernel<<<((size_t)n * 64 + THREADS - 1) / THREADS, THREADS, 0, stream>>>(
        h0b, dinvv, offs, csr, b1, hbb, nullptr, n, 1);
    spmm_bf16_kernel<<<((size_t)n * 64 + THREADS - 1) / THREADS, THREADS, 0, stream>>>(
        hbb, dinvv, offs, csr, nullptr, nullptr, agg2, n, 0);
    gemm23_kernel<<<(n + 63) / 64, THREADS, 0, stream>>>(agg2, W2, W3, b2, b3, outm, outl, n);
}

// Round 11
// 445.097 us; speedup vs baseline: 1.5868x; 1.0814x over previous
//
#include <hip/hip_runtime.h>

// GCN encoder: h = relu(A_norm @ (x@W1) + b1); mean = (A_norm@h)@W2+b2; logstd = (A_norm@h)@W3+b3
// R2: 3-stage parallel scan. R3/R4: spmm ping-pong pipeline (161->108us).
// R5: packed u64 atomic histogram -> atomic-free fill. R6: split-bf16 MFMA gemm1.
// R7/R9: slab/XCD-pin spmm: fixed FETCH but structural overhead cost more. Reverted.
// R10: bf16 feature storage halves gather bytes (spmm 108->~60us). Total 481us.
// R11: deg_count (77us) is at the scattered-atomic floor (1 atomic/edge, ~21 Gops/s
//     memory-side) AND independent of gemm1 (~80us MFMA-bound). Fuse them into ONE
//     kernel with interleaved block roles (1 gemm : 8 deg) -> atomic latency hides
//     under MFMA work (same principle as MFMA/VALU wave co-scheduling).

#define THREADS 256
#define SCAN_CHUNK 2048   // elements per block in the scan kernels (256 thr x 8)
#define D 4               // spmm pipeline group size (2 groups in flight = 8 feat loads)
#define ILV 9             // fused kernel: 1 gemm block per 8 deg blocks

#define DEG_MASK ((1ULL << 40) - 1)
#define CNT_SHIFT 40

typedef __attribute__((ext_vector_type(8))) short short8;   // 8 bf16 (4 VGPRs)
typedef __attribute__((ext_vector_type(4))) float floatx4;  // MFMA acc

__device__ __forceinline__ unsigned short f32_to_bf16(float v) {
    return (unsigned short)((__float_as_uint(v) + 0x8000u) >> 16);  // round-half-up
}

// ---------------- zero init (ws is poisoned 0xAA every launch) ----------------
__global__ __launch_bounds__(THREADS) void zero_kernel(float* __restrict__ p, int n) {
    int i = blockIdx.x * THREADS + threadIdx.x;
    if (i < n) p[i] = 0.0f;   // bit pattern 0 also valid for u64 packed counters
}

// ---------------- W1 split+transpose: Wt_hi/lo[n=128][k=512] bf16 ----------------
__global__ __launch_bounds__(THREADS) void wsplit_kernel(
    const float* __restrict__ W, unsigned short* __restrict__ hi,
    unsigned short* __restrict__ lo) {
    int id = blockIdx.x * THREADS + threadIdx.x;   // 65536 = 512*128
    if (id >= 512 * 128) return;
    int k = id >> 7, n = id & 127;
    float v = W[id];                               // W[k][n]
    unsigned int b = __float_as_uint(v);
    unsigned short h = (unsigned short)(b >> 16);  // truncated hi bf16
    float fh = __uint_as_float(b & 0xFFFF0000u);
    unsigned short l = (unsigned short)(__float_as_uint(v - fh) >> 16);  // residual bf16
    hi[n * 512 + k] = h;
    lo[n * 512 + k] = l;
}

// ---------------- FUSED: gemm1 (MFMA, role bid%ILV==0) + deg histogram (other) ------
// gemm: h0b[M,128] (bf16) = x[M,512] @ W1 via split-bf16 (3 MFMA products, err ~2^-17).
// deg:  one packed u64 atomic per edge (count<<40 | fixpoint weight), old>>40 = rank.
// Interleaved roles keep atomic-queue blocks and MFMA blocks co-resident on every CU.
__global__ __launch_bounds__(THREADS) void fused_gemm1_deg_kernel(
    const float* __restrict__ A, const unsigned short* __restrict__ Wth,
    const unsigned short* __restrict__ Wtl, unsigned short* __restrict__ C, int M,
    const int* __restrict__ ei, const float* __restrict__ ew,
    unsigned long long* __restrict__ deg_cnt, int* __restrict__ rank, int E,
    int gemm_blocks) {
    __shared__ unsigned short As[2][64][72];    // [hi/lo][m][k]
    __shared__ unsigned short Bs[2][128][72];   // [hi/lo][n][k]
    int bid = blockIdx.x;
    int role = bid % ILV;
    int t = threadIdx.x;

    if (role != 0) {
        // ---------------- deg/histogram role ----------------
        int db = (bid / ILV) * (ILV - 1) + (role - 1);
        int e = db * THREADS + t;
        if (e >= E) return;
        int d = ei[E + e];
        float w = ew[e];
        unsigned long long q = (unsigned long long)(w * 4294967296.0f);
        unsigned long long old = atomicAdd(&deg_cnt[d], (1ULL << CNT_SHIFT) | q);
        rank[e] = (int)(old >> CNT_SHIFT);
        return;
    }

    // ---------------- gemm1 role ----------------
    int gb = bid / ILV;
    if (gb >= gemm_blocks) return;
    int brow0 = gb * 64;
    int arow = t >> 2, akq = (t & 3) * 16;      // A: 64 rows x 4 chunks of 16 f32
    int bn = t >> 1, bkoff = (t & 1) * 32;      // B: 128 rows x 2 chunks of 32 bf16
    int wid = t >> 6, lane = t & 63;
    int wr = wid >> 1, wc = wid & 1;            // 2x2 wave grid
    int lm = lane & 15, lk = (lane >> 4) * 8;
    floatx4 acc[2][4];
#pragma unroll
    for (int i = 0; i < 2; i++)
#pragma unroll
        for (int j = 0; j < 4; j++) acc[i][j] = (floatx4)0.0f;

    int gr = brow0 + arow;
    for (int k0 = 0; k0 < 512; k0 += 64) {
        __syncthreads();
        {
            const float* ap = &A[(size_t)gr * 512 + k0 + akq];
#pragma unroll
            for (int i = 0; i < 4; ++i) {
                float4 v = (gr < M) ? *(const float4*)&ap[i * 4]
                                    : make_float4(0.f, 0.f, 0.f, 0.f);
                float e4[4] = {v.x, v.y, v.z, v.w};
                ushort4 h4, l4;
                unsigned short* hp = (unsigned short*)&h4;
                unsigned short* lp = (unsigned short*)&l4;
#pragma unroll
                for (int c = 0; c < 4; ++c) {
                    unsigned int b = __float_as_uint(e4[c]);
                    hp[c] = (unsigned short)(b >> 16);
                    float fh = __uint_as_float(b & 0xFFFF0000u);
                    lp[c] = (unsigned short)(__float_as_uint(e4[c] - fh) >> 16);
                }
                *(ushort4*)&As[0][arow][akq + i * 4] = h4;
                *(ushort4*)&As[1][arow][akq + i * 4] = l4;
            }
        }
        {
            const unsigned short* bh = &Wth[(size_t)bn * 512 + k0 + bkoff];
            const unsigned short* bl = &Wtl[(size_t)bn * 512 + k0 + bkoff];
#pragma unroll
            for (int s = 0; s < 4; ++s) {
                *(float4*)&Bs[0][bn][bkoff + s * 8] = *(const float4*)&bh[s * 8];
                *(float4*)&Bs[1][bn][bkoff + s * 8] = *(const float4*)&bl[s * 8];
            }
        }
        __syncthreads();
#pragma unroll
        for (int kc = 0; kc < 2; ++kc) {
            int kb = kc * 32 + lk;
            short8 ah[2], al[2], bh[4], bl[4];
#pragma unroll
            for (int mf = 0; mf < 2; ++mf) {
                ah[mf] = *(const short8*)&As[0][wr * 32 + mf * 16 + lm][kb];
                al[mf] = *(const short8*)&As[1][wr * 32 + mf * 16 + lm][kb];
            }
#pragma unroll
            for (int nf = 0; nf < 4; ++nf) {
                bh[nf] = *(const short8*)&Bs[0][wc * 64 + nf * 16 + lm][kb];
                bl[nf] = *(const short8*)&Bs[1][wc * 64 + nf * 16 + lm][kb];
            }
#pragma unroll
            for (int mf = 0; mf < 2; ++mf)
#pragma unroll
                for (int nf = 0; nf < 4; ++nf) {
                    acc[mf][nf] = __builtin_amdgcn_mfma_f32_16x16x32_bf16(
                        ah[mf], bh[nf], acc[mf][nf], 0, 0, 0);
                    acc[mf][nf] = __builtin_amdgcn_mfma_f32_16x16x32_bf16(
                        ah[mf], bl[nf], acc[mf][nf], 0, 0, 0);
                    acc[mf][nf] = __builtin_amdgcn_mfma_f32_16x16x32_bf16(
                        al[mf], bh[nf], acc[mf][nf], 0, 0, 0);
                }
        }
    }
    // epilogue: C/D layout col = lane&15, row = (lane>>4)*4 + reg; bf16 row-major out
#pragma unroll
    for (int mf = 0; mf < 2; ++mf) {
        int rbase = brow0 + wr * 32 + mf * 16 + (lane >> 4) * 4;
#pragma unroll
        for (int nf = 0; nf < 4; ++nf) {
            int col = wc * 64 + nf * 16 + lm;
#pragma unroll
            for (int r = 0; r < 4; ++r) {
                int g = rbase + r;
                if (g < M) C[(size_t)g * 128 + col] = f32_to_bf16(acc[mf][nf][r]);
            }
        }
    }
}

// ---------------- parallel scan stage 1: block sums + dinv ----------------
__global__ __launch_bounds__(THREADS) void scan_part1(
    const unsigned long long* __restrict__ deg_cnt,
    float* __restrict__ dinvv, int* __restrict__ partials, int n) {
    int t = threadIdx.x;
    int base = blockIdx.x * SCAN_CHUNK + t * 8;
    int s = 0;
#pragma unroll
    for (int i = 0; i < 8; ++i) {
        int idx = base + i;
        if (idx < n) {
            unsigned long long v = deg_cnt[idx];
            s += (int)(v >> CNT_SHIFT);
            float dg = (float)(v & DEG_MASK) * 0x1p-32f;   // un-fixed-point the weight sum
            dinvv[idx] = rsqrtf(dg + 1.0f);                // +1 = self-loop weight
        }
    }
    __shared__ int sm[THREADS];
    sm[t] = s;
    __syncthreads();
    for (int off = THREADS / 2; off > 0; off >>= 1) {
        if (t < off) sm[t] += sm[t + off];
        __syncthreads();
    }
    if (t == 0) partials[blockIdx.x] = sm[0];
}

// ---------------- parallel scan stage 2: exclusive scan of block partials ----------------
__global__ __launch_bounds__(1024) void scan_part2(int* __restrict__ partials, int nb) {
    __shared__ int s[1024];
    int t = threadIdx.x;
    int v = (t < nb) ? partials[t] : 0;
    s[t] = v;
    __syncthreads();
    for (int off = 1; off < 1024; off <<= 1) {
        int x = (t >= off) ? s[t - off] : 0;
        __syncthreads();
        s[t] += x;
        __syncthreads();
    }
    if (t < nb) partials[t] = s[t] - v;   // exclusive prefix
}

// ---------------- parallel scan stage 3: per-block local scan -> offs ----------------
__global__ __launch_bounds__(THREADS) void scan_part3(
    const unsigned long long* __restrict__ deg_cnt, const int* __restrict__ partials,
    int* __restrict__ offs, int n) {
    int t = threadIdx.x;
    int base = blockIdx.x * SCAN_CHUNK + t * 8;
    int loc[8];
    int s = 0;
#pragma unroll
    for (int i = 0; i < 8; ++i) {
        int idx = base + i;
        int c = (idx < n) ? (int)(deg_cnt[idx] >> CNT_SHIFT) : 0;
        loc[i] = c;
        s += c;
    }
    __shared__ int sm[THREADS];
    sm[t] = s;
    __syncthreads();
    for (int off = 1; off < THREADS; off <<= 1) {
        int x = (t >= off) ? sm[t - off] : 0;
        __syncthreads();
        sm[t] += x;
        __syncthreads();
    }
    int run = partials[blockIdx.x] + sm[t] - s;   // exclusive prefix of this thread's range
#pragma unroll
    for (int i = 0; i < 8; ++i) {
        int idx = base + i;
        if (idx < n) {
            offs[idx] = run;
            run += loc[i];
            if (idx == n - 1) offs[n] = run;
        }
    }
}

// ---------------- fill CSR: atomic-free (pos = offs[dst] + rank) ----------------
__global__ __launch_bounds__(THREADS) void fill_kernel(
    const int* __restrict__ ei, const float* __restrict__ ew,
    const float* __restrict__ dinvv, const int* __restrict__ offs,
    const int* __restrict__ rank, int2* __restrict__ csr, int E) {
    int e = blockIdx.x * THREADS + threadIdx.x;
    if (e >= E) return;
    int s = ei[e], d = ei[E + e];
    int pos = offs[d] + rank[e];
    csr[pos] = make_int2(s, __float_as_int(dinvv[s] * ew[e] * dinvv[d]));
}

// ---------------- SpMM (bf16 gather): out[d,:] = sum_e w_e*feat[src_e,:] + dinv^2*feat[d,:]
// one wave per dst node; 2 channels per lane (1 dword of 2 bf16); software-pipelined:
// csr scalar path (readfirstlane'd dst), feat loads ping-pong with 2 groups of D in flight.
// Output: bf16 (outb) for next gather, or f32 (outf) for gemm23.
__global__ __launch_bounds__(THREADS) void spmm_bf16_kernel(
    const unsigned short* __restrict__ feat, const float* __restrict__ dinvv,
    const int* __restrict__ offs, const int2* __restrict__ csr,
    const float* __restrict__ bias, unsigned short* __restrict__ outb,
    float* __restrict__ outf, int n, int do_relu) {
    int gw = (blockIdx.x * THREADS + threadIdx.x) >> 6;
    int lane = threadIdx.x & 63;
    if (gw >= n) return;
    const int d = __builtin_amdgcn_readfirstlane(gw);   // wave-uniform -> SALU/s_load path
    float di = dinvv[d];
    float sw = di * di;                                 // self-loop norm = 1/deg
    const unsigned int* __restrict__ f1 = (const unsigned int*)feat + lane;  // word per 2ch
    unsigned int sv = f1[(size_t)d * 64];
    float2 acc;
    acc.x = __uint_as_float(sv << 16) * sw;
    acc.y = __uint_as_float(sv & 0xFFFF0000u) * sw;
    int j0 = offs[d];
    int m = offs[d + 1] - j0;
    const int2* __restrict__ cp = csr + j0;

    int2 eA[D], eB[D];
    float wA[D], wB[D];
    unsigned int vA[D], vB[D];

    // prologue: csr groups 0 and 1; feat group 0 in flight
#pragma unroll
    for (int i = 0; i < D; ++i) if (i < m) eA[i] = cp[i];
#pragma unroll
    for (int i = 0; i < D; ++i) if (D + i < m) eB[i] = cp[D + i];
#pragma unroll
    for (int i = 0; i < D; ++i) if (i < m) {
        wA[i] = __int_as_float(eA[i].y);
        vA[i] = f1[(size_t)eA[i].x * 64];
    }

    int g = 0;
    for (; g + 4 * D <= m; g += 2 * D) {
        // half 1: consume group g (vA/wA); eB holds csr(g+D)
#pragma unroll
        for (int i = 0; i < D; ++i) eA[i] = cp[g + 2 * D + i];       // csr for g+2D
#pragma unroll
        for (int i = 0; i < D; ++i) {
            wB[i] = __int_as_float(eB[i].y);
            vB[i] = f1[(size_t)eB[i].x * 64];                        // feat for g+D
        }
#pragma unroll
        for (int i = 0; i < D; ++i) {
            acc.x = fmaf(wA[i], __uint_as_float(vA[i] << 16), acc.x);
            acc.y = fmaf(wA[i], __uint_as_float(vA[i] & 0xFFFF0000u), acc.y);
        }
        // half 2: consume group g+D (vB/wB); eA holds csr(g+2D)
#pragma unroll
        for (int i = 0; i < D; ++i) eB[i] = cp[g + 3 * D + i];       // csr for g+3D
#pragma unroll
        for (int i = 0; i < D; ++i) {
            wA[i] = __int_as_float(eA[i].y);
            vA[i] = f1[(size_t)eA[i].x * 64];                        // feat for g+2D
        }
#pragma unroll
        for (int i = 0; i < D; ++i) {
            acc.x = fmaf(wB[i], __uint_as_float(vB[i] << 16), acc.x);
            acc.y = fmaf(wB[i], __uint_as_float(vB[i] & 0xFFFF0000u), acc.y);
        }
    }
    // epilogue: group g in flight (vA), csr for group g+D resident in eB (guarded)
#pragma unroll
    for (int i = 0; i < D; ++i) if (g + i < m) {
        acc.x = fmaf(wA[i], __uint_as_float(vA[i] << 16), acc.x);
        acc.y = fmaf(wA[i], __uint_as_float(vA[i] & 0xFFFF0000u), acc.y);
    }
    g += D;
#pragma unroll
    for (int i = 0; i < D; ++i) if (g + i < m) {
        float w = __int_as_float(eB[i].y);
        unsigned int v = f1[(size_t)eB[i].x * 64];
        acc.x = fmaf(w, __uint_as_float(v << 16), acc.x);
        acc.y = fmaf(w, __uint_as_float(v & 0xFFFF0000u), acc.y);
    }
    g += D;
    for (; g < m; ++g) {
        int2 e = cp[g];
        float w = __int_as_float(e.y);
        unsigned int v = f1[(size_t)e.x * 64];
        acc.x = fmaf(w, __uint_as_float(v << 16), acc.x);
        acc.y = fmaf(w, __uint_as_float(v & 0xFFFF0000u), acc.y);
    }

    if (bias) {
        float2 b = *(const float2*)&bias[lane * 2];
        acc.x += b.x;
        acc.y += b.y;
    }
    if (do_relu) {
        acc.x = fmaxf(acc.x, 0.0f);
        acc.y = fmaxf(acc.y, 0.0f);
    }
    if (outb) {
        unsigned int lo = (__float_as_uint(acc.x) + 0x8000u) >> 16;
        unsigned int hi = (__float_as_uint(acc.y) + 0x8000u) & 0xFFFF0000u;
        ((unsigned int*)outb)[(size_t)d * 64 + lane] = hi | lo;
    } else {
        ((float2*)outf)[(size_t)d * 64 + lane] = acc;
    }
}

// ---------------- GEMM23: [mean|logstd] = agg2[M,128] @ [W2|W3][128,128] + [b2|b3] ------
__global__ __launch_bounds__(THREADS) void gemm23_kernel(
    const float* __restrict__ A, const float* __restrict__ W2,
    const float* __restrict__ W3, const float* __restrict__ b2,
    const float* __restrict__ b3, float* __restrict__ outm,
    float* __restrict__ outl, int M) {
    __shared__ float As[16][68];
    __shared__ float Bs[16][128];
    int t = threadIdx.x;
    int ty = t >> 4, tx = t & 15;
    int brow0 = blockIdx.x * 64;
    int arow = t >> 2, aq = t & 3;
    int bkr = t >> 5, bcol = (t & 31) * 4;
    float acc[4][8];
#pragma unroll
    for (int i = 0; i < 4; i++)
#pragma unroll
        for (int j = 0; j < 8; j++) acc[i][j] = 0.0f;
    int gr = brow0 + arow;
    const float4 z4 = make_float4(0.f, 0.f, 0.f, 0.f);
    for (int k0 = 0; k0 < 128; k0 += 16) {
        float4 av = (gr < M) ? *(const float4*)&A[(size_t)gr * 128 + k0 + aq * 4] : z4;
        int k1 = k0 + bkr, k2 = k0 + bkr + 8;
        float4 b0 = (bcol < 64) ? *(const float4*)&W2[(size_t)k1 * 64 + bcol]
                                : *(const float4*)&W3[(size_t)k1 * 64 + bcol - 64];
        float4 b1 = (bcol < 64) ? *(const float4*)&W2[(size_t)k2 * 64 + bcol]
                                : *(const float4*)&W3[(size_t)k2 * 64 + bcol - 64];
        __syncthreads();
        As[aq * 4 + 0][arow] = av.x;
        As[aq * 4 + 1][arow] = av.y;
        As[aq * 4 + 2][arow] = av.z;
        As[aq * 4 + 3][arow] = av.w;
        *(float4*)&Bs[bkr][bcol] = b0;
        *(float4*)&Bs[bkr + 8][bcol] = b1;
        __syncthreads();
#pragma unroll
        for (int kk = 0; kk < 16; ++kk) {
            float4 a = *(const float4*)&As[kk][ty * 4];
            float4 p0 = *(const float4*)&Bs[kk][tx * 8];
            float4 p1 = *(const float4*)&Bs[kk][tx * 8 + 4];
            float av_[4] = {a.x, a.y, a.z, a.w};
            float bv_[8] = {p0.x, p0.y, p0.z, p0.w, p1.x, p1.y, p1.z, p1.w};
#pragma unroll
            for (int i = 0; i < 4; i++)
#pragma unroll
                for (int j = 0; j < 8; j++)
                    acc[i][j] = fmaf(av_[i], bv_[j], acc[i][j]);
        }
    }
    bool is_mean = (tx < 8);
    int c = is_mean ? tx * 8 : tx * 8 - 64;
    const float* bb = is_mean ? b2 : b3;
    float* op = is_mean ? outm : outl;
    float4 bias0 = *(const float4*)&bb[c];
    float4 bias1 = *(const float4*)&bb[c + 4];
#pragma unroll
    for (int i = 0; i < 4; i++) {
        int r = brow0 + ty * 4 + i;
        if (r < M) {
            *(float4*)&op[(size_t)r * 64 + c] =
                make_float4(acc[i][0] + bias0.x, acc[i][1] + bias0.y,
                            acc[i][2] + bias0.z, acc[i][3] + bias0.w);
            *(float4*)&op[(size_t)r * 64 + c + 4] =
                make_float4(acc[i][4] + bias1.x, acc[i][5] + bias1.y,
                            acc[i][6] + bias1.z, acc[i][7] + bias1.w);
        }
    }
}

extern "C" void kernel_launch(void* const* d_in, const int* in_sizes, int n_in,
                              void* d_out, int out_size, void* d_ws, size_t ws_size,
                              hipStream_t stream) {
    const float* x  = (const float*)d_in[0];
    const int*   ei = (const int*)d_in[1];
    const float* ew = (const float*)d_in[2];
    const float* W1 = (const float*)d_in[3];
    const float* b1 = (const float*)d_in[4];
    const float* W2 = (const float*)d_in[5];
    const float* b2 = (const float*)d_in[6];
    const float* W3 = (const float*)d_in[7];
    const float* b3 = (const float*)d_in[8];

    const int n = in_sizes[0] / 512;   // 50000
    const int E = in_sizes[2];         // 1600000
    const int nb_scan = (n + SCAN_CHUNK - 1) / SCAN_CHUNK;   // 25

    char* p = (char*)d_ws;
    auto alloc = [&](size_t bytes) {
        char* q = p;
        p += (bytes + 511) & ~(size_t)511;
        return q;
    };
    unsigned long long* deg_cnt = (unsigned long long*)alloc((size_t)n * 8);
    float* dinvv  = (float*)alloc((size_t)n * 4);
    int*   offs   = (int*)alloc((size_t)(n + 1) * 4);
    int*   rank   = (int*)alloc((size_t)E * 4);
    int*   partials = (int*)alloc((size_t)nb_scan * 4);
    int2*  csr    = (int2*)alloc((size_t)E * 8);
    unsigned short* Wth = (unsigned short*)alloc((size_t)512 * 128 * 2);
    unsigned short* Wtl = (unsigned short*)alloc((size_t)512 * 128 * 2);
    unsigned short* h0b = (unsigned short*)alloc((size_t)n * 128 * 2);  // bf16 x@W1
    unsigned short* hbb = (unsigned short*)alloc((size_t)n * 128 * 2);  // bf16 relu'd hidden
    float* agg2   = (float*)alloc((size_t)n * 128 * 4);                 // f32 A@hb

    float* outm = (float*)d_out;
    float* outl = outm + (size_t)n * 64;

    // fused grid: gemm blocks at bid%ILV==0 (ids 0..gemm_blocks-1), deg blocks elsewhere
    const int gemm_blocks = (n + 63) / 64;                  // 782
    const int deg_blocks  = (E + THREADS - 1) / THREADS;    // 6250
    int fused_grid = gemm_blocks * ILV;                     // covers all gemm ids
    {   // ensure deg ids cover deg_blocks: db = (bid/ILV)*(ILV-1) + (r-1)
        int need = (deg_blocks + (ILV - 1) - 1) / (ILV - 1);  // full groups of 8
        int alt = need * ILV;
        if (alt > fused_grid) fused_grid = alt;
    }

    zero_kernel<<<(2 * n + THREADS - 1) / THREADS, THREADS, 0, stream>>>((float*)deg_cnt, 2 * n);
    wsplit_kernel<<<(512 * 128 + THREADS - 1) / THREADS, THREADS, 0, stream>>>(W1, Wth, Wtl);
    fused_gemm1_deg_kernel<<<fused_grid, THREADS, 0, stream>>>(
        x, Wth, Wtl, h0b, n, ei, ew, deg_cnt, rank, E, gemm_blocks);
    scan_part1<<<nb_scan, THREADS, 0, stream>>>(deg_cnt, dinvv, partials, n);
    scan_part2<<<1, 1024, 0, stream>>>(partials, nb_scan);
    scan_part3<<<nb_scan, THREADS, 0, stream>>>(deg_cnt, partials, offs, n);
    fill_kernel<<<(E + THREADS - 1) / THREADS, THREADS, 0, stream>>>(ei, ew, dinvv, offs,
                                                                     rank, csr, E);
    spmm_bf16_kernel<<<((size_t)n * 64 + THREADS - 1) / THREADS, THREADS, 0, stream>>>(
        h0b, dinvv, offs, csr, b1, hbb, nullptr, n, 1);
    spmm_bf16_kernel<<<((size_t)n * 64 + THREADS - 1) / THREADS, THREADS, 0, stream>>>(
        hbb, dinvv, offs, csr, nullptr, nullptr, agg2, n, 0);
    gemm23_kernel<<<(n + 63) / 64, THREADS, 0, stream>>>(agg2, W2, W3, b2, b3, outm, outl, n);
}